// Round 8
// baseline (2604.037 us; speedup 1.0000x reference)
//
#include <hip/hip_runtime.h>
#include <hip/hip_bf16.h>
#include <stdint.h>

#define T_STEPS 512
#define BATCH   256
#define DIN     85
#define HDIM    512
#define NOUT    33

#define GRP   16     // blocks per group
#define BBLK  16     // batch rows per group
#define HS    32     // H columns per block
#define LDA   1040   // bytes per padded row of h A-tile (520 elems, 16B-aligned)
#define LDX   208    // bytes per padded row of x A-tile (104 elems)

typedef __attribute__((ext_vector_type(8))) short s8v;       // 8 x bf16
typedef __attribute__((ext_vector_type(4))) float f4v;       // MFMA accumulator
typedef __attribute__((ext_vector_type(4))) uint32_t u32x4;  // 16B chunk

__device__ __forceinline__ uint16_t f2bf(float f) {
    uint32_t x = __builtin_bit_cast(uint32_t, f);
    uint32_t r = (x + 0x7fffu + ((x >> 16) & 1u)) >> 16;
    return (uint16_t)r;
}
__device__ __forceinline__ float sigm(float v) {
    v = fminf(fmaxf(v, -30.f), 30.f);
    return 1.f / (1.f + __expf(-v));
}
__device__ __forceinline__ float tanh_f(float v) {
    v = fminf(fmaxf(v, -15.f), 15.f);
    float e = __expf(2.f * v);
    return (e - 1.f) / (e + 1.f);
}
__device__ __forceinline__ s8v cvt8(const float* p) {
    s8v v;
#pragma unroll
    for (int j = 0; j < 8; ++j) v[j] = (short)f2bf(p[j]);
    return v;
}

// agent-coherent 4x16B bulk load (sc0 sc1 = coherence point), single waitcnt
__device__ __forceinline__ void load16_coh(const uint32_t* p0, const uint32_t* p1,
                                           const uint32_t* p2, const uint32_t* p3,
                                           u32x4& a, u32x4& b, u32x4& c, u32x4& d) {
    asm volatile("global_load_dwordx4 %0, %4, off sc0 sc1\n\t"
                 "global_load_dwordx4 %1, %5, off sc0 sc1\n\t"
                 "global_load_dwordx4 %2, %6, off sc0 sc1\n\t"
                 "global_load_dwordx4 %3, %7, off sc0 sc1\n\t"
                 "s_waitcnt vmcnt(0)"
                 : "=&v"(a), "=&v"(b), "=&v"(c), "=&v"(d)
                 : "v"(p0), "v"(p1), "v"(p2), "v"(p3)
                 : "memory");
}

// Persistent recurrence kernel. 256 blocks = 16 groups x 16 members.
// Group owns 16 batch rows; member owns 32 H columns (x4 gates, one per wave).
// Weights live in registers as MFMA B-fragments for the whole kernel.
// r8 exchange protocol (attacks MALL request-rate congestion identified r7):
//   - producers: 64 h agent-stores per wave -> per-wave `s_waitcnt vmcnt(0)`
//     (stores acked at coherence point) -> lane0 stores ONE wave-flag.
//     No block barrier on the producer path.
//   - consumers: poll 64 wave-flags with 64 lanes = 2 cache lines per wave
//     per round (~2k reqs/round device-wide vs r7's 262k), then ONE bulk
//     dwordx4 refill of the data.
//   - x prefetch issued after the flag store so no barrier drains HBM loads.
__global__ __launch_bounds__(256, 1) void lstm_rec(
    const float* __restrict__ x,
    const float* __restrict__ Wxi, const float* __restrict__ Wxf,
    const float* __restrict__ Wxo, const float* __restrict__ Wxc,
    const float* __restrict__ Whi, const float* __restrict__ bhi,
    const float* __restrict__ Whf, const float* __restrict__ bhf,
    const float* __restrict__ Who, const float* __restrict__ bho,
    const float* __restrict__ Whc, const float* __restrict__ bhc,
    uint16_t* __restrict__ hbuf,      // [T_STEPS+1][BATCH][HDIM] bf16 (scratch)
    uint32_t* __restrict__ flags)     // [16][T_STEPS][64] wave-flags (zeroed)
{
    __shared__ __align__(16) uint8_t hA[16 * LDA];   // 16.6 KB
    __shared__ __align__(16) uint8_t xA[16 * LDX];   // 3.3 KB
    __shared__ float gbuf[4 * 16 * 33];              // 8.4 KB

    const int tid  = threadIdx.x;
    const int bid  = blockIdx.x;
    const int xcd  = bid & 7;
    const int slot = bid >> 3;
    const int grp  = xcd * 2 + (slot >> 4);
    const int mem  = slot & 15;
    const int b0   = grp * BBLK;
    const int hs   = mem * HS;

    const int wave  = tid >> 6;       // gate: 0=i 1=f 2=o 3=c
    const int lane  = tid & 63;
    const int col16 = lane & 15;
    const int quad  = lane >> 4;

    const float* Wh  = (wave == 0) ? Whi : (wave == 1) ? Whf : (wave == 2) ? Who : Whc;
    const float* Wxp = (wave == 0) ? Wxi : (wave == 1) ? Wxf : (wave == 2) ? Wxo : Wxc;

    // ---- B-fragments (weights) into registers, once (fp32 -> bf16 RNE) ----
    s8v bh[2][16];
#pragma unroll
    for (int nt = 0; nt < 2; ++nt) {
        const float* rowp = Wh + (size_t)(hs + nt * 16 + col16) * HDIM;
#pragma unroll
        for (int kt = 0; kt < 16; ++kt)
            bh[nt][kt] = cvt8(rowp + kt * 32 + quad * 8);
    }
    s8v bx[2][3];
#pragma unroll
    for (int nt = 0; nt < 2; ++nt) {
        const float* rowp = Wxp + (size_t)(hs + nt * 16 + col16) * DIN;
#pragma unroll
        for (int kt = 0; kt < 3; ++kt) {
            s8v v;
#pragma unroll
            for (int j = 0; j < 8; ++j) {
                int k = kt * 32 + quad * 8 + j;
                v[j] = (k < DIN) ? (short)f2bf(rowp[k]) : (short)0;
            }
            bx[nt][kt] = v;
        }
    }

    // ---- pointwise mapping: thread -> (row r, cols c0,c0+1) of 16x32 slice ----
    const int r  = tid >> 4;
    const int c0 = (tid & 15) * 2;
    const float bi0 = bhi[hs + c0], bi1 = bhi[hs + c0 + 1];
    const float bf0 = bhf[hs + c0], bf1 = bhf[hs + c0 + 1];
    const float bo0 = bho[hs + c0], bo1 = bho[hs + c0 + 1];
    const float bc0 = bhc[hs + c0], bc1 = bhc[hs + c0 + 1];
    float C0 = 0.f, C1 = 0.f;

    uint32_t* hbuf32 = (uint32_t*)hbuf;
    const size_t hslot = ((size_t)(b0 + r) * HDIM + hs + c0) >> 1;

    // ---- refill chunk mapping: chunk c = tid + 256q -> row c>>6, 16B col c&63
    const int rrow[4] = { tid >> 6, (tid + 256) >> 6, (tid + 512) >> 6, (tid + 768) >> 6 };
    const int rc8     = tid & 63;

    // ---- x prefetch (fp32 registers) ----
    float xreg[6];
    auto load_x = [&](int t) {
#pragma unroll
        for (int j = 0; j < 6; ++j) {
            int v = tid + j * 256;
            int row = v / 96, k = v % 96;
            xreg[j] = (k < DIN) ? x[(size_t)(t * BATCH + b0 + row) * DIN + k] : 0.f;
        }
    };
    auto store_x = [&]() {
#pragma unroll
        for (int j = 0; j < 6; ++j) {
            int v = tid + j * 256;
            int row = v / 96, k = v % 96;
            *(uint16_t*)(xA + row * LDX + k * 2) = f2bf(xreg[j]);
        }
    };

    // init: h(0)=0 in LDS, stage x(0)
    load_x(0);
    for (int j = tid; j < 16 * LDA / 16; j += 256) {
        s8v z;
#pragma unroll
        for (int q = 0; q < 8; ++q) z[q] = 0;
        ((s8v*)hA)[j] = z;
    }
    store_x();
    __syncthreads();

    for (int t = 0; t < T_STEPS; ++t) {
        // ---- GEMM: pre-activations for this wave's gate, 16 rows x 32 cols ----
        f4v acc0 = {0.f, 0.f, 0.f, 0.f}, acc1 = {0.f, 0.f, 0.f, 0.f};
#pragma unroll
        for (int kt = 0; kt < 16; ++kt) {
            s8v a = *(const s8v*)(hA + col16 * LDA + kt * 64 + quad * 16);
            acc0 = __builtin_amdgcn_mfma_f32_16x16x32_bf16(a, bh[0][kt], acc0, 0, 0, 0);
            acc1 = __builtin_amdgcn_mfma_f32_16x16x32_bf16(a, bh[1][kt], acc1, 0, 0, 0);
        }
#pragma unroll
        for (int kt = 0; kt < 3; ++kt) {
            s8v a = *(const s8v*)(xA + col16 * LDX + kt * 64 + quad * 16);
            acc0 = __builtin_amdgcn_mfma_f32_16x16x32_bf16(a, bx[0][kt], acc0, 0, 0, 0);
            acc1 = __builtin_amdgcn_mfma_f32_16x16x32_bf16(a, bx[1][kt], acc1, 0, 0, 0);
        }
        // C/D layout: col = lane&15, row = quad*4 + reg
#pragma unroll
        for (int rr = 0; rr < 4; ++rr) {
            int b = quad * 4 + rr;
            gbuf[(wave * 16 + b) * 33 + col16]      = acc0[rr];
            gbuf[(wave * 16 + b) * 33 + 16 + col16] = acc1[rr];
        }

        __syncthreads();   // cheap: only LDS outstanding (no VMEM in flight)

        // ---- pointwise ----
        float pi0 = gbuf[(0 * 16 + r) * 33 + c0] + bi0;
        float pi1 = gbuf[(0 * 16 + r) * 33 + c0 + 1] + bi1;
        float pf0 = gbuf[(1 * 16 + r) * 33 + c0] + bf0;
        float pf1 = gbuf[(1 * 16 + r) * 33 + c0 + 1] + bf1;
        float po0 = gbuf[(2 * 16 + r) * 33 + c0] + bo0;
        float po1 = gbuf[(2 * 16 + r) * 33 + c0 + 1] + bo1;
        float pc0 = gbuf[(3 * 16 + r) * 33 + c0] + bc0;
        float pc1 = gbuf[(3 * 16 + r) * 33 + c0 + 1] + bc1;

        float I0 = sigm(pi0), F0 = sigm(pf0), O0 = sigm(po0), G0 = tanh_f(pc0);
        float I1 = sigm(pi1), F1 = sigm(pf1), O1 = sigm(po1), G1 = tanh_f(pc1);
        C0 = F0 * C0 + I0 * G0;
        C1 = F1 * C1 + I1 * G1;
        float h0 = O0 * tanh_f(C0);
        float h1 = O1 * tanh_f(C1);

        // h publish: agent store (coherence point)
        uint32_t packed = (uint32_t)f2bf(h0) | ((uint32_t)f2bf(h1) << 16);
        __hip_atomic_store(&hbuf32[(size_t)(t + 1) * (BATCH * HDIM / 2) + hslot],
                           packed, __ATOMIC_RELAXED, __HIP_MEMORY_SCOPE_AGENT);

        if (t == T_STEPS - 1) break;

        // per-wave release: wait own stores acked at coherence point, then
        // one wave-flag store. No block barrier on the producer path.
        asm volatile("s_waitcnt vmcnt(0)" ::: "memory");
        uint32_t* fl = flags + ((size_t)grp * T_STEPS + t) * 64;
        if (lane == 0)
            __hip_atomic_store(&fl[mem * 4 + wave], 1u,
                               __ATOMIC_RELAXED, __HIP_MEMORY_SCOPE_AGENT);

        load_x(t + 1);   // HBM loads fly through poll + refill

        // ---- poll 64 wave-flags: 2 cache lines per wave per round ----
        int rounds = 0;
        for (;;) {
            uint32_t v = __hip_atomic_load(&fl[lane], __ATOMIC_RELAXED,
                                           __HIP_MEMORY_SCOPE_AGENT);
            if (!__ballot(v == 0)) break;
            if (++rounds > (1 << 20)) break;   // never hang
        }

        // ---- bulk refill h(t+1) tile: one dwordx4 burst ----
        const uint32_t* src = hbuf32 + (size_t)(t + 1) * (BATCH * HDIM / 2)
                                     + (size_t)b0 * (HDIM / 2);
        const uint32_t* p0 = src + (size_t)rrow[0] * (HDIM / 2) + rc8 * 4;
        const uint32_t* p1 = src + (size_t)rrow[1] * (HDIM / 2) + rc8 * 4;
        const uint32_t* p2 = src + (size_t)rrow[2] * (HDIM / 2) + rc8 * 4;
        const uint32_t* p3 = src + (size_t)rrow[3] * (HDIM / 2) + rc8 * 4;
        u32x4 v0, v1, v2, v3;
        load16_coh(p0, p1, p2, p3, v0, v1, v2, v3);
        *(u32x4*)(hA + rrow[0] * LDA + rc8 * 16) = v0;
        *(u32x4*)(hA + rrow[1] * LDA + rc8 * 16) = v1;
        *(u32x4*)(hA + rrow[2] * LDA + rc8 * 16) = v2;
        *(u32x4*)(hA + rrow[3] * LDA + rc8 * 16) = v3;

        store_x();
        __syncthreads();   // hA/xA staged for next step
    }
}

// Readout: out[t,b,:] = h[t+1] @ Wro^T + bro.  MFMA, N padded 33->48. fp32 out.
__global__ __launch_bounds__(256, 1) void lstm_out(
    const uint16_t* __restrict__ hbuf,
    const float* __restrict__ Wro, const float* __restrict__ bro,
    float* __restrict__ out)
{
    __shared__ __align__(16) uint8_t hT[64 * LDA];   // 66.6 KB

    const int tid   = threadIdx.x;
    const int bid   = blockIdx.x;
    const int wave  = tid >> 6;
    const int lane  = tid & 63;
    const int col16 = lane & 15;
    const int quad  = lane >> 4;

    s8v bw[3][16];
    float bias[3];
#pragma unroll
    for (int nt = 0; nt < 3; ++nt) {
        int o = nt * 16 + col16;
        bias[nt] = (o < NOUT) ? bro[o] : 0.f;
#pragma unroll
        for (int kt = 0; kt < 16; ++kt) {
            if (o < NOUT) {
                bw[nt][kt] = cvt8(Wro + (size_t)o * HDIM + kt * 32 + quad * 8);
            } else {
                s8v z;
#pragma unroll
                for (int q = 0; q < 8; ++q) z[q] = 0;
                bw[nt][kt] = z;
            }
        }
    }

    const uint16_t* hsrc = hbuf + (size_t)BATCH * HDIM;  // skip t=0 slot

    for (int sub = 0; sub < 8; ++sub) {
        size_t row0 = (size_t)bid * 512 + (size_t)sub * 64;
#pragma unroll
        for (int j = 0; j < 16; ++j) {
            int v = tid + j * 256;
            int row = v >> 6, c8 = v & 63;
            s8v val = *(const s8v*)(hsrc + (row0 + row) * HDIM + c8 * 8);
            *(s8v*)(hT + row * LDA + c8 * 16) = val;
        }
        __syncthreads();

        f4v acc[3];
#pragma unroll
        for (int nt = 0; nt < 3; ++nt) acc[nt] = (f4v){0.f, 0.f, 0.f, 0.f};
#pragma unroll
        for (int kt = 0; kt < 16; ++kt) {
            s8v a = *(const s8v*)(hT + (wave * 16 + col16) * LDA + kt * 64 + quad * 16);
#pragma unroll
            for (int nt = 0; nt < 3; ++nt)
                acc[nt] = __builtin_amdgcn_mfma_f32_16x16x32_bf16(a, bw[nt][kt], acc[nt], 0, 0, 0);
        }
#pragma unroll
        for (int nt = 0; nt < 3; ++nt) {
            int o = nt * 16 + col16;
            if (o < NOUT) {
#pragma unroll
                for (int rr = 0; rr < 4; ++rr) {
                    size_t rg = row0 + (size_t)wave * 16 + quad * 4 + rr;
                    out[rg * NOUT + o] = acc[nt][rr] + bias[nt];
                }
            }
        }
        __syncthreads();
    }
}

extern "C" void kernel_launch(void* const* d_in, const int* in_sizes, int n_in,
                              void* d_out, int out_size, void* d_ws, size_t ws_size,
                              hipStream_t stream)
{
    const float* x   = (const float*)d_in[0];
    const float* Wxi = (const float*)d_in[1];
    const float* Wxf = (const float*)d_in[2];
    const float* Wxo = (const float*)d_in[3];
    const float* Wxc = (const float*)d_in[4];
    const float* Whi = (const float*)d_in[5];
    const float* bhi = (const float*)d_in[6];
    const float* Whf = (const float*)d_in[7];
    const float* bhf = (const float*)d_in[8];
    const float* Who = (const float*)d_in[9];
    const float* bho = (const float*)d_in[10];
    const float* Whc = (const float*)d_in[11];
    const float* bhc = (const float*)d_in[12];
    const float* Wro = (const float*)d_in[13];
    const float* bro = (const float*)d_in[14];
    float* out = (float*)d_out;

    uint8_t* ws = (uint8_t*)d_ws;
    uint32_t* flags = (uint32_t*)ws;                      // 16*512*64*4 = 2 MB
    uint16_t* hbuf  = (uint16_t*)(ws + (size_t)16 * T_STEPS * 64 * 4);

    hipMemsetAsync(flags, 0, (size_t)16 * T_STEPS * 64 * sizeof(uint32_t), stream);
    lstm_rec<<<256, 256, 0, stream>>>(x, Wxi, Wxf, Wxo, Wxc,
                                      Whi, bhi, Whf, bhf, Who, bho, Whc, bhc,
                                      hbuf, flags);
    lstm_out<<<256, 256, 0, stream>>>(hbuf, Wro, bro, out);
}